// Round 9
// baseline (616.761 us; speedup 1.0000x reference)
//
#include <hip/hip_runtime.h>
#include <hip/hip_fp16.h>
#include <math.h>

typedef __attribute__((ext_vector_type(8))) _Float16 f16x8;
typedef __attribute__((ext_vector_type(4))) float f32x4;

#define PAD_PLANE (66 * 66 * 256)   // padded image: rows/cols -1..64 -> 0..65

__device__ inline ushort f2h(float f) { return __half_as_ushort(__float2half_rn(f)); }
__device__ inline __half2 u2h2(uint u) { union { uint u; __half2 h; } x; x.u = u; return x.h; }
__device__ inline uint h22u(__half2 h) { union { uint u; __half2 h; } x; x.h = h; return x.u; }

union frag_u { uint4 u; f16x8 v; };

__device__ inline void glds16(const ushort* g, ushort* l) {
  __builtin_amdgcn_global_load_lds((const __attribute__((address_space(1))) uint*)g,
                                   (__attribute__((address_space(3))) uint*)l, 16, 0, 0);
}

// ---------------- zero halo-padded buffers ----------------
__global__ void k_zero(float4* __restrict__ p, int n) {
  int stride = gridDim.x * blockDim.x;
  float4 z = {0.f, 0.f, 0.f, 0.f};
  for (int i = blockIdx.x * blockDim.x + threadIdx.x; i < n; i += stride) p[i] = z;
}

// ---------------- weight prep: fp32 -> fp16 [s=(p,cic)][co][kk] ----------------
__global__ void k_prep(const float* __restrict__ w1, const float* __restrict__ wd,
                       const float* __restrict__ woff, const float* __restrict__ wmod,
                       const float* __restrict__ wds,
                       ushort* __restrict__ wb1, ushort* __restrict__ wbd,
                       ushort* __restrict__ wbom, ushort* __restrict__ wbds) {
  int stride = gridDim.x * blockDim.x;
  int t0 = blockIdx.x * blockDim.x + threadIdx.x;
  for (int s = t0; s < 9 * 8 * 256 * 32; s += stride) {
    int kk = s & 31, co = (s >> 5) & 255, cic = (s >> 13) & 7, p = s >> 16;
    int ci = cic * 32 + kk;
    wb1[s] = f2h(w1[(co * 256 + ci) * 9 + p]);
    wbd[s] = f2h(wd[(co * 256 + ci) * 9 + p]);
  }
  for (int s = t0; s < 9 * 8 * 32 * 32; s += stride) {
    int kk = s & 31, co = (s >> 5) & 31, cic = (s >> 10) & 7, p = s >> 13;
    int ci = cic * 32 + kk;
    float v = 0.f;
    if (co < 18) v = woff[(co * 256 + ci) * 9 + p];
    else if (co < 27) v = wmod[((co - 18) * 256 + ci) * 9 + p];
    wbom[s] = f2h(v);
  }
  for (int s = t0; s < 8 * 256 * 32; s += stride) {
    int kk = s & 31, co = (s >> 5) & 255, cic = s >> 13;
    wbds[s] = f2h(wds[co * 256 + cic * 32 + kk]);
  }
}

// ---------------- x NCHW fp32 -> padded NHWC fp16 ----------------
__global__ __launch_bounds__(256) void k_x2nhwc(const float* __restrict__ x,
                                                ushort* __restrict__ xnp) {
  __shared__ __align__(16) float sT[64 * 68];
  const int b = blockIdx.x, h = blockIdx.y, t = threadIdx.x;
  for (int chunk = 0; chunk < 4; ++chunk) {
    const int c0 = chunk * 64;
    {
      int w4 = (t & 15) * 4, cl = t >> 4;
      #pragma unroll
      for (int i = 0; i < 4; ++i) {
        int c = cl * 4 + i;
        float4 v = *(const float4*)&x[((b * 256 + c0 + c) * 64 + h) * 64 + w4];
        *(float4*)&sT[c * 68 + w4] = v;
      }
    }
    __syncthreads();
    {
      int w = t & 63, cg = t >> 6;
      #pragma unroll
      for (int i = 0; i < 2; ++i) {
        int cg2 = cg * 2 + i;
        uint ou[4];
        #pragma unroll
        for (int k2 = 0; k2 < 4; ++k2) {
          float lo = sT[(cg2 * 8 + k2 * 2) * 68 + w];
          float hi = sT[(cg2 * 8 + k2 * 2 + 1) * 68 + w];
          ou[k2] = (uint)f2h(lo) | ((uint)f2h(hi) << 16);
        }
        *(uint4*)&xnp[(size_t)((b * 66 + h + 1) * 66 + w + 1) * 256 + c0 + cg2 * 8] = *(uint4*)ou;
      }
    }
    __syncthreads();
  }
}

// ---------------- big conv (3x3 / 1x1): glds dbuf-A, reg-pipelined B, fp16 ----------------
// grid (8,128) = (b, 2h+half) -> XCD=b, 4 blocks/CU. Wave wv: co [wv*64,+64), 32 px.
template<int NTAP>
__global__ __launch_bounds__(256, 4) void k_convbig(const ushort* __restrict__ anp,
                                                    const ushort* __restrict__ wB,
                                                    ushort* __restrict__ ob,
                                                    float* __restrict__ part) {
  __shared__ __align__(16) ushort sA[2][32 * 256];
  const int b = blockIdx.x, hh = blockIdx.y;
  const int h = hh >> 1, ph = (hh & 1) * 32;
  const int t = threadIdx.x, lane = t & 63, wv = t >> 6;
  const int cow = wv * 64;
  const int krow = lane >> 4;
  const ushort* bplane = anp + (size_t)b * PAD_PLANE;
  f32x4 acc[2][4];
  #pragma unroll
  for (int m = 0; m < 2; ++m)
    #pragma unroll
    for (int n = 0; n < 4; ++n) acc[m][n] = (f32x4){0.f, 0.f, 0.f, 0.f};

  const int spx = wv * 8 + (lane >> 5);  // px for j=0 (+2 per j)
  const int slot = lane & 31;

  auto stage = [&](int p, int buf) {
    int ky = (NTAP == 9) ? p / 3 : 1, kx = (NTAP == 9) ? p % 3 : 1;
    int y = h + ky;                          // padded row
    #pragma unroll
    for (int j = 0; j < 4; ++j) {
      int px = spx + j * 2;
      int gsrc = slot ^ (px & 7);
      int sx = ph + px + kx;                 // padded col
      const ushort* g = bplane + (y * 66 + sx) * 256 + gsrc * 8;
      glds16(g, &sA[buf][wv * 2048 + j * 512]);
    }
  };
  auto loadB = [&](frag_u (&bu)[4], int s) {
    #pragma unroll
    for (int n = 0; n < 4; ++n)
      bu[n].u = *(const uint4*)(wB + (s * 256 + cow + n * 16 + (lane & 15)) * 32 + krow * 8);
  };

  stage(0, 0);
  __syncthreads();
  int cur = 0;
  for (int p = 0; p < NTAP; ++p) {
    if (p + 1 < NTAP) stage(p + 1, cur ^ 1);
    frag_u bu[2][4];
    loadB(bu[0], p * 8);
    #pragma unroll
    for (int cic = 0; cic < 8; ++cic) {
      if (cic < 7) loadB(bu[(cic + 1) & 1], p * 8 + cic + 1);
      frag_u au[2];
      #pragma unroll
      for (int m = 0; m < 2; ++m)
        au[m].u = *(const uint4*)&sA[cur][(m * 16 + (lane & 15)) * 256 + (((cic * 4 + krow) ^ (lane & 7)) * 8)];
      #pragma unroll
      for (int m = 0; m < 2; ++m)
        #pragma unroll
        for (int n = 0; n < 4; ++n)
          acc[m][n] = __builtin_amdgcn_mfma_f32_16x16x32_f16(au[m].v, bu[cic & 1][n].v, acc[m][n], 0, 0, 0);
    }
    __syncthreads();
    cur ^= 1;
  }
  // ---- BN partials
  const int blk2 = b * 128 + hh;
  #pragma unroll
  for (int n = 0; n < 4; ++n) {
    float s1 = 0.f, s2 = 0.f;
    #pragma unroll
    for (int m = 0; m < 2; ++m)
      #pragma unroll
      for (int r = 0; r < 4; ++r) { float v = acc[m][n][r]; s1 += v; s2 += v * v; }
    s1 += __shfl_xor(s1, 16); s1 += __shfl_xor(s1, 32);
    s2 += __shfl_xor(s2, 16); s2 += __shfl_xor(s2, 32);
    if (lane < 16) {
      int co = cow + n * 16 + lane;
      part[co * 1024 + blk2] = s1;
      part[262144 + co * 1024 + blk2] = s2;
    }
  }
  // ---- coalesced fp16 store via swizzled LDS transpose
  __syncthreads();
  #pragma unroll
  for (int m = 0; m < 2; ++m) {
    int pxo = m * 16 + (lane >> 4) * 4;
    #pragma unroll
    for (int n = 0; n < 4; ++n) {
      int co = cow + n * 16 + (lane & 15);
      #pragma unroll
      for (int r = 0; r < 4; ++r) {
        int px = pxo + r;
        sA[0][px * 256 + (co ^ ((px & 7) << 3))] = f2h(acc[m][n][r]);
      }
    }
  }
  __syncthreads();
  const int row0 = (b * 64 + h) * 64 + ph;
  const int px_l = t & 31, seg = t >> 5;
  #pragma unroll
  for (int j = 0; j < 4; ++j)
    *(uint4*)&ob[(size_t)(row0 + px_l) * 256 + seg * 32 + j * 8] =
        *(const uint4*)&sA[0][px_l * 256 + (((seg * 4 + j) ^ (px_l & 7)) * 8)];
}

// ---------------- offset/mask conv: glds dbuf-A, 32 co ----------------
__global__ __launch_bounds__(256, 4) void k_convom(const ushort* __restrict__ anp,
                                                   const ushort* __restrict__ wB,
                                                   const float* __restrict__ boff,
                                                   const float* __restrict__ bmod,
                                                   float* __restrict__ om) {
  __shared__ __align__(16) ushort sA[2][32 * 256];
  const int b = blockIdx.x, hh = blockIdx.y;
  const int h = hh >> 1, ph = (hh & 1) * 32;
  const int t = threadIdx.x, lane = t & 63, wv = t >> 6;
  const int mloc = wv & 1, nt = wv >> 1;
  const int krow = lane >> 4;
  const ushort* bplane = anp + (size_t)b * PAD_PLANE;
  f32x4 acc = (f32x4){0.f, 0.f, 0.f, 0.f};
  const int spx = wv * 8 + (lane >> 5);
  const int slot = lane & 31;

  auto stage = [&](int p, int buf) {
    int ky = p / 3, kx = p % 3;
    int y = h + ky;
    #pragma unroll
    for (int j = 0; j < 4; ++j) {
      int px = spx + j * 2;
      int gsrc = slot ^ (px & 7);
      int sx = ph + px + kx;
      const ushort* g = bplane + (y * 66 + sx) * 256 + gsrc * 8;
      glds16(g, &sA[buf][wv * 2048 + j * 512]);
    }
  };

  stage(0, 0);
  __syncthreads();
  int cur = 0;
  const int lpx = mloc * 16 + (lane & 15);
  for (int p = 0; p < 9; ++p) {
    if (p < 8) stage(p + 1, cur ^ 1);
    frag_u bu[2];
    bu[0].u = *(const uint4*)(wB + (p * 8 * 32 + nt * 16 + (lane & 15)) * 32 + krow * 8);
    #pragma unroll
    for (int cic = 0; cic < 8; ++cic) {
      if (cic < 7)
        bu[(cic + 1) & 1].u = *(const uint4*)(wB + ((p * 8 + cic + 1) * 32 + nt * 16 + (lane & 15)) * 32 + krow * 8);
      frag_u au;
      au.u = *(const uint4*)&sA[cur][lpx * 256 + (((cic * 4 + krow) ^ (lane & 7)) * 8)];
      acc = __builtin_amdgcn_mfma_f32_16x16x32_f16(au.v, bu[cic & 1].v, acc, 0, 0, 0);
    }
    __syncthreads();
    cur ^= 1;
  }
  int co = nt * 16 + (lane & 15);
  #pragma unroll
  for (int r = 0; r < 4; ++r) {
    int px = ph + mloc * 16 + (lane >> 4) * 4 + r;
    int row = (b * 64 + h) * 64 + px;
    float v = acc[r];
    float o;
    if (co < 18) o = v + boff[co];
    else if (co < 27) { float mm = v + bmod[co - 18]; o = 2.f / (1.f + __expf(-mm)); }
    else o = 0.f;
    om[row * 32 + co] = o;
  }
}

// ---------------- deformable conv: T14 split-gather, dbuf sA ----------------
__global__ __launch_bounds__(256, 4) void k_deform(const ushort* __restrict__ anp,
                                                   const float* __restrict__ om,
                                                   const ushort* __restrict__ wB,
                                                   ushort* __restrict__ ob,
                                                   float* __restrict__ part) {
  __shared__ __align__(16) ushort sA[2][32 * 256];
  const int b = blockIdx.x, hh = blockIdx.y;
  const int h = hh >> 1, ph = (hh & 1) * 32;
  const int t = threadIdx.x, lane = t & 63, wv = t >> 6;
  const int cow = wv * 64;
  const int krow = lane >> 4;
  const int px_l = t & 31, seg = t >> 5;
  const int gpx = ph + px_l;
  const int row = (b * 64 + h) * 64 + gpx;
  const ushort* bplane = anp + (size_t)b * PAD_PLANE;
  f32x4 acc[2][4];
  #pragma unroll
  for (int m = 0; m < 2; ++m)
    #pragma unroll
    for (int n = 0; n < 4; ++n) acc[m][n] = (f32x4){0.f, 0.f, 0.f, 0.f};

  __half2 wh0, wh1, wh2, wh3;
  uint o00, o01, o10, o11;
  uint4 s00[2], s01[2], s10[2], s11[2];

  auto spec = [&](int p) {
    float dy = om[row * 32 + 2 * p];
    float dx = om[row * 32 + 2 * p + 1];
    float mk = om[row * 32 + 18 + p];
    float py = (float)(h + p / 3 - 1) + dy;
    float pxx = (float)(gpx + p % 3 - 1) + dx;
    float fy = floorf(py), fx = floorf(pxx);
    float ly = py - fy, lx = pxx - fx;
    int y0 = (int)fy, x0 = (int)fx;
    bool vy0 = ((unsigned)y0 < 64u), vy1 = ((unsigned)(y0 + 1) < 64u);
    bool vx0 = ((unsigned)x0 < 64u), vx1 = ((unsigned)(x0 + 1) < 64u);
    wh0 = __float2half2_rn((1.f - ly) * (1.f - lx) * mk * ((vy0 && vx0) ? 1.f : 0.f));
    wh1 = __float2half2_rn((1.f - ly) * lx * mk * ((vy0 && vx1) ? 1.f : 0.f));
    wh2 = __float2half2_rn(ly * (1.f - lx) * mk * ((vy1 && vx0) ? 1.f : 0.f));
    wh3 = __float2half2_rn(ly * lx * mk * ((vy1 && vx1) ? 1.f : 0.f));
    int y0c = min(max(y0, 0), 63), y1c = min(max(y0 + 1, 0), 63);
    int x0c = min(max(x0, 0), 63), x1c = min(max(x0 + 1, 0), 63);
    o00 = (uint)(((y0c + 1) * 66 + x0c + 1) * 256 + seg * 32);
    o01 = (uint)(((y0c + 1) * 66 + x1c + 1) * 256 + seg * 32);
    o10 = (uint)(((y1c + 1) * 66 + x0c + 1) * 256 + seg * 32);
    o11 = (uint)(((y1c + 1) * 66 + x1c + 1) * 256 + seg * 32);
  };
  auto issueJ = [&](int j0) {
    #pragma unroll
    for (int jj = 0; jj < 2; ++jj) {
      int j = j0 + jj;
      s00[jj] = *(const uint4*)(bplane + o00 + j * 8);
      s01[jj] = *(const uint4*)(bplane + o01 + j * 8);
      s10[jj] = *(const uint4*)(bplane + o10 + j * 8);
      s11[jj] = *(const uint4*)(bplane + o11 + j * 8);
    }
  };
  auto blendJ = [&](int buf, int j0) {
    #pragma unroll
    for (int jj = 0; jj < 2; ++jj) {
      int j = j0 + jj;
      uint ou[4];
      #pragma unroll
      for (int q = 0; q < 4; ++q) {
        __half2 r2 = __hmul2(u2h2(((const uint*)&s00[jj])[q]), wh0);
        r2 = __hfma2(u2h2(((const uint*)&s01[jj])[q]), wh1, r2);
        r2 = __hfma2(u2h2(((const uint*)&s10[jj])[q]), wh2, r2);
        r2 = __hfma2(u2h2(((const uint*)&s11[jj])[q]), wh3, r2);
        ou[q] = h22u(r2);
      }
      *(uint4*)&sA[buf][px_l * 256 + (((seg * 4 + j) ^ (px_l & 7)) * 8)] = *(uint4*)ou;
    }
  };
  auto loadB = [&](frag_u (&bu)[4], int s) {
    #pragma unroll
    for (int n = 0; n < 4; ++n)
      bu[n].u = *(const uint4*)(wB + (s * 256 + cow + n * 16 + (lane & 15)) * 32 + krow * 8);
  };

  spec(0);
  issueJ(0); blendJ(0, 0);
  issueJ(2); blendJ(0, 2);
  __syncthreads();
  int cur = 0;
  for (int p = 0; p < 9; ++p) {
    if (p < 8) { spec(p + 1); issueJ(0); }
    #pragma unroll
    for (int cic = 0; cic < 4; ++cic) {
      frag_u bu[4], au[2];
      loadB(bu, p * 8 + cic);
      #pragma unroll
      for (int m = 0; m < 2; ++m)
        au[m].u = *(const uint4*)&sA[cur][(m * 16 + (lane & 15)) * 256 + (((cic * 4 + krow) ^ (lane & 7)) * 8)];
      #pragma unroll
      for (int m = 0; m < 2; ++m)
        #pragma unroll
        for (int n = 0; n < 4; ++n)
          acc[m][n] = __builtin_amdgcn_mfma_f32_16x16x32_f16(au[m].v, bu[n].v, acc[m][n], 0, 0, 0);
    }
    if (p < 8) { blendJ(cur ^ 1, 0); issueJ(2); }
    #pragma unroll
    for (int cic = 4; cic < 8; ++cic) {
      frag_u bu[4], au[2];
      loadB(bu, p * 8 + cic);
      #pragma unroll
      for (int m = 0; m < 2; ++m)
        au[m].u = *(const uint4*)&sA[cur][(m * 16 + (lane & 15)) * 256 + (((cic * 4 + krow) ^ (lane & 7)) * 8)];
      #pragma unroll
      for (int m = 0; m < 2; ++m)
        #pragma unroll
        for (int n = 0; n < 4; ++n)
          acc[m][n] = __builtin_amdgcn_mfma_f32_16x16x32_f16(au[m].v, bu[n].v, acc[m][n], 0, 0, 0);
    }
    if (p < 8) blendJ(cur ^ 1, 2);
    __syncthreads();
    cur ^= 1;
  }
  const int blk2 = b * 128 + hh;
  #pragma unroll
  for (int n = 0; n < 4; ++n) {
    float s1 = 0.f, s2 = 0.f;
    #pragma unroll
    for (int m = 0; m < 2; ++m)
      #pragma unroll
      for (int r = 0; r < 4; ++r) { float v = acc[m][n][r]; s1 += v; s2 += v * v; }
    s1 += __shfl_xor(s1, 16); s1 += __shfl_xor(s1, 32);
    s2 += __shfl_xor(s2, 16); s2 += __shfl_xor(s2, 32);
    if (lane < 16) {
      int co = cow + n * 16 + lane;
      part[co * 1024 + blk2] = s1;
      part[262144 + co * 1024 + blk2] = s2;
    }
  }
  __syncthreads();
  #pragma unroll
  for (int m = 0; m < 2; ++m) {
    int pxo = m * 16 + (lane >> 4) * 4;
    #pragma unroll
    for (int n = 0; n < 4; ++n) {
      int co = cow + n * 16 + (lane & 15);
      #pragma unroll
      for (int r = 0; r < 4; ++r) {
        int px = pxo + r;
        sA[0][px * 256 + (co ^ ((px & 7) << 3))] = f2h(acc[m][n][r]);
      }
    }
  }
  __syncthreads();
  const int row0 = (b * 64 + h) * 64 + ph;
  #pragma unroll
  for (int j = 0; j < 4; ++j)
    *(uint4*)&ob[(size_t)(row0 + px_l) * 256 + seg * 32 + j * 8] =
        *(const uint4*)&sA[0][px_l * 256 + (((seg * 4 + j) ^ (px_l & 7)) * 8)];
}

// ---------------- BN stats final reduce (part: [2][256][1024]) ----------------
__global__ void k_statB(const float* __restrict__ part, const float* __restrict__ g,
                        const float* __restrict__ bt, float* __restrict__ scale,
                        float* __restrict__ shift) {
  __shared__ float s2buf[256];
  const int tid = threadIdx.x;
  const int c = tid & 255, which = tid >> 8;
  const float4* p4 = (const float4*)(part + which * 262144 + c * 1024);
  float s = 0.f;
  for (int r = 0; r < 256; ++r) { float4 v = p4[r]; s += v.x + v.y + v.z + v.w; }
  if (which) s2buf[c] = s;
  __syncthreads();
  if (!which) {
    const float inv = 1.f / 32768.f;
    float m = s * inv;
    float var = s2buf[c] * inv - m * m;
    float a = g[c] * rsqrtf(var + 1e-5f);
    scale[c] = a;
    shift[c] = bt[c] - m * a;
  }
}

// ---------------- BN+ReLU: t1 fp16 dense NHWC -> out1 padded NHWC ----------------
__global__ void k_bnrelu(const ushort* __restrict__ t, const float* __restrict__ scale,
                         const float* __restrict__ shift, ushort* __restrict__ op) {
  int stride = gridDim.x * blockDim.x;
  for (int i = blockIdx.x * blockDim.x + threadIdx.x; i < 1048576; i += stride) {
    uint4 v = ((const uint4*)t)[i];
    int c0 = (i & 31) * 8;
    uint ou[4];
    #pragma unroll
    for (int q = 0; q < 4; ++q) {
      float2 f = __half22float2(u2h2(((const uint*)&v)[q]));
      float sa = scale[c0 + 2 * q], sb = scale[c0 + 2 * q + 1];
      float ha = shift[c0 + 2 * q], hb = shift[c0 + 2 * q + 1];
      float qa = fmaxf(f.x * sa + ha, 0.f);
      float qb = fmaxf(f.y * sb + hb, 0.f);
      ou[q] = (uint)f2h(qa) | ((uint)f2h(qb) << 16);
    }
    int brow = i >> 11;               // (b,h) row: 2048 uint4 each
    int bb = brow >> 6, hrow = brow & 63;
    int xcol = (i >> 5) & 63, chunk = i & 31;
    size_t di = (size_t)((bb * 66 + hrow + 1) * 66 + xcol + 1) * 32 + chunk;
    ((uint4*)op)[di] = *(uint4*)ou;
  }
}

// ---------------- final: relu(bn2(t2)+bn3(res)), fp16 dense NHWC -> fp32 NCHW ----------------
__global__ __launch_bounds__(256) void k_final(const ushort* __restrict__ t2, const ushort* __restrict__ res,
                                               const float* __restrict__ s2p, const float* __restrict__ sh2p,
                                               const float* __restrict__ s3p, const float* __restrict__ sh3p,
                                               float* __restrict__ o) {
  __shared__ __align__(16) float sT[64 * 68];
  const int b = blockIdx.x, h = blockIdx.y, t = threadIdx.x;
  const int row0 = (b * 64 + h) * 64;
  for (int chunk = 0; chunk < 4; ++chunk) {
    const int c0 = chunk * 64;
    {
      int px = t >> 2, s4 = t & 3;
      int cl = s4 * 16;
      int rbase = (row0 + px) * 256 + c0 + cl;
      uint4 a0 = *(const uint4*)&t2[rbase];
      uint4 a1 = *(const uint4*)&t2[rbase + 8];
      uint4 r0 = *(const uint4*)&res[rbase];
      uint4 r1 = *(const uint4*)&res[rbase + 8];
      #pragma unroll
      for (int q = 0; q < 8; ++q) {
        uint ua = (q < 4) ? ((const uint*)&a0)[q] : ((const uint*)&a1)[q - 4];
        uint ur = (q < 4) ? ((const uint*)&r0)[q] : ((const uint*)&r1)[q - 4];
        float2 fa = __half22float2(u2h2(ua));
        float2 fr = __half22float2(u2h2(ur));
        int ce = cl + 2 * q, codd = ce + 1;
        sT[ce * 68 + px] = fmaxf(fa.x * s2p[c0 + ce] + sh2p[c0 + ce] + fr.x * s3p[c0 + ce] + sh3p[c0 + ce], 0.f);
        sT[codd * 68 + px] = fmaxf(fa.y * s2p[c0 + codd] + sh2p[c0 + codd] + fr.y * s3p[c0 + codd] + sh3p[c0 + codd], 0.f);
      }
    }
    __syncthreads();
    {
      int cl = t & 63, wseg = t >> 6;
      int obase = ((b * 256 + c0 + cl) * 64 + h) * 64 + wseg * 16;
      #pragma unroll
      for (int j = 0; j < 4; ++j) {
        float4 q;
        q.x = sT[cl * 68 + wseg * 16 + j * 4 + 0];
        q.y = sT[cl * 68 + wseg * 16 + j * 4 + 1];
        q.z = sT[cl * 68 + wseg * 16 + j * 4 + 2];
        q.w = sT[cl * 68 + wseg * 16 + j * 4 + 3];
        *(float4*)&o[obase + j * 4] = q;
      }
    }
    __syncthreads();
  }
}

extern "C" void kernel_launch(void* const* d_in, const int* in_sizes, int n_in,
                              void* d_out, int out_size, void* d_ws, size_t ws_size,
                              hipStream_t stream) {
  const float* x    = (const float*)d_in[0];
  const float* w1   = (const float*)d_in[2];
  const float* g1   = (const float*)d_in[4];
  const float* bt1  = (const float*)d_in[5];
  const float* woff = (const float*)d_in[6];
  const float* boff = (const float*)d_in[7];
  const float* wmod = (const float*)d_in[8];
  const float* bmod = (const float*)d_in[9];
  const float* wd   = (const float*)d_in[10];
  const float* g2   = (const float*)d_in[12];
  const float* bt2  = (const float*)d_in[13];
  const float* wds  = (const float*)d_in[14];
  const float* g3   = (const float*)d_in[16];
  const float* bt3  = (const float*)d_in[17];

  float* ws = (float*)d_ws;
  ushort* wb1   = (ushort*)ws;                    // 294912 f32
  ushort* wbd   = (ushort*)(ws + 294912);         // 294912
  ushort* wbom  = (ushort*)(ws + 589824);         // 36864
  ushort* wbds  = (ushort*)(ws + 626688);         // 32768
  float*  SC    = ws + 659456;                    // 2048
  float*  part1 = ws + 661504;                    // 524288
  float*  part2 = ws + 1185792;                   // 524288
  float*  part3 = ws + 1710080;                   // 524288
  ushort* xnp   = (ushort*)(ws + 2234368);        // 4460544 f32 (padded)
  ushort* out1p = (ushort*)(ws + 6694912);        // 4460544 f32 (padded)
  ushort* t1b   = (ushort*)(ws + 11155456);       // 4194304
  ushort* t2b   = (ushort*)(ws + 15349760);       // 4194304
  ushort* resb  = (ushort*)(ws + 19544064);       // 4194304
  float*  om    = ws + 23738368;                  // 1048576 (end 24786944 f32 ~ 95 MB)

  dim3 g64(8, 64), g128(8, 128);
  k_zero<<<2048, 256, 0, stream>>>((float4*)xnp, 2230272);  // xnp+out1p contiguous
  k_prep<<<512, 256, 0, stream>>>(w1, wd, woff, wmod, wds, wb1, wbd, wbom, wbds);
  k_x2nhwc<<<g64, 256, 0, stream>>>(x, xnp);
  k_convbig<9><<<g128, 256, 0, stream>>>(xnp, wb1, t1b, part1);
  k_statB<<<1, 512, 0, stream>>>(part1, g1, bt1, SC, SC + 256);
  k_bnrelu<<<2048, 256, 0, stream>>>(t1b, SC, SC + 256, out1p);
  k_convom<<<g128, 256, 0, stream>>>(out1p, wbom, boff, bmod, om);
  k_deform<<<g128, 256, 0, stream>>>(out1p, om, wbd, t2b, part2);
  k_statB<<<1, 512, 0, stream>>>(part2, g2, bt2, SC + 512, SC + 768);
  k_convbig<1><<<g128, 256, 0, stream>>>(xnp, wbds, resb, part3);
  k_statB<<<1, 512, 0, stream>>>(part3, g3, bt3, SC + 1024, SC + 1280);
  k_final<<<g64, 256, 0, stream>>>(t2b, resb, SC + 512, SC + 768, SC + 1024, SC + 1280, (float*)d_out);
}

// Round 12
// 454.135 us; speedup vs baseline: 1.3581x; 1.3581x over previous
//
#include <hip/hip_runtime.h>
#include <hip/hip_fp16.h>
#include <math.h>

typedef __attribute__((ext_vector_type(8))) _Float16 f16x8;
typedef __attribute__((ext_vector_type(4))) float f32x4;

#define PLANE 4096

__device__ inline ushort f2h(float f) { return __half_as_ushort(__float2half_rn(f)); }
__device__ inline __half2 u2h2(uint u) { union { uint u; __half2 h; } x; x.u = u; return x.h; }
__device__ inline uint h22u(__half2 h) { union { uint u; __half2 h; } x; x.h = h; return x.u; }

union frag_u { uint4 u; f16x8 v; };

// ---------------- weight prep: fp32 -> fp16 [s=(p,cic)][co][kk] ----------------
__global__ void k_prep(const float* __restrict__ w1, const float* __restrict__ wd,
                       const float* __restrict__ woff, const float* __restrict__ wmod,
                       const float* __restrict__ wds,
                       ushort* __restrict__ wb1, ushort* __restrict__ wbd,
                       ushort* __restrict__ wbom, ushort* __restrict__ wbds) {
  int stride = gridDim.x * blockDim.x;
  int t0 = blockIdx.x * blockDim.x + threadIdx.x;
  for (int s = t0; s < 9 * 8 * 256 * 32; s += stride) {
    int kk = s & 31, co = (s >> 5) & 255, cic = (s >> 13) & 7, p = s >> 16;
    int ci = cic * 32 + kk;
    wb1[s] = f2h(w1[(co * 256 + ci) * 9 + p]);
    wbd[s] = f2h(wd[(co * 256 + ci) * 9 + p]);
  }
  for (int s = t0; s < 9 * 8 * 32 * 32; s += stride) {
    int kk = s & 31, co = (s >> 5) & 31, cic = (s >> 10) & 7, p = s >> 13;
    int ci = cic * 32 + kk;
    float v = 0.f;
    if (co < 18) v = woff[(co * 256 + ci) * 9 + p];
    else if (co < 27) v = wmod[((co - 18) * 256 + ci) * 9 + p];
    wbom[s] = f2h(v);
  }
  for (int s = t0; s < 8 * 256 * 32; s += stride) {
    int kk = s & 31, co = (s >> 5) & 255, cic = s >> 13;
    wbds[s] = f2h(wds[co * 256 + cic * 32 + kk]);
  }
}

// ---------------- x NCHW fp32 -> xn NHWC fp16 (grid (b,h) for XCD pinning) ----------------
__global__ __launch_bounds__(256) void k_x2nhwc(const float* __restrict__ x,
                                                ushort* __restrict__ xn) {
  __shared__ __align__(16) float sT[64 * 68];
  const int b = blockIdx.x, h = blockIdx.y, t = threadIdx.x;
  for (int chunk = 0; chunk < 4; ++chunk) {
    const int c0 = chunk * 64;
    {
      int w4 = (t & 15) * 4, cl = t >> 4;
      #pragma unroll
      for (int i = 0; i < 4; ++i) {
        int c = cl * 4 + i;
        float4 v = *(const float4*)&x[((b * 256 + c0 + c) * 64 + h) * 64 + w4];
        *(float4*)&sT[c * 68 + w4] = v;
      }
    }
    __syncthreads();
    {
      int w = t & 63, cg = t >> 6;
      #pragma unroll
      for (int i = 0; i < 2; ++i) {
        int cg2 = cg * 2 + i;
        uint ou[4];
        #pragma unroll
        for (int k2 = 0; k2 < 4; ++k2) {
          float lo = sT[(cg2 * 8 + k2 * 2) * 68 + w];
          float hi = sT[(cg2 * 8 + k2 * 2 + 1) * 68 + w];
          ou[k2] = (uint)f2h(lo) | ((uint)f2h(hi) << 16);
        }
        *(uint4*)&xn[(((b * 64 + h) * 64 + w) * 256) + c0 + cg2 * 8] = *(uint4*)ou;
      }
    }
    __syncthreads();
  }
}

// ---------------- big conv (3x3 pad1 / 1x1): 512 thr, 8 waves, B reg-pipelined ----------------
// grid (8,64) = (b,h) -> XCD = b. Wave wv owns co [wv*32,+32), all 64 px.
template<int NTAP>
__global__ __launch_bounds__(512, 4) void k_convbig(const ushort* __restrict__ an,
                                                    const ushort* __restrict__ wB,
                                                    ushort* __restrict__ ob,
                                                    float* __restrict__ part) {
  __shared__ __align__(16) ushort sA[64 * 256];
  const int b = blockIdx.x, h = blockIdx.y, t = threadIdx.x;
  const int lane = t & 63, wv = t >> 6;
  const int cow = wv * 32;
  const int krow = lane >> 4;
  f32x4 acc[4][2];
  #pragma unroll
  for (int m = 0; m < 4; ++m)
    #pragma unroll
    for (int n = 0; n < 2; ++n) acc[m][n] = (f32x4){0.f, 0.f, 0.f, 0.f};

  const int chunk = t & 31, pr = t >> 5;  // chunk: 8-ch group, pr: 0..15
  // 2-deep B ping-pong, hoisted across taps
  frag_u bu[2][2];
  #pragma unroll
  for (int n = 0; n < 2; ++n)
    bu[0][n].u = *(const uint4*)(wB + (cow + n * 16 + (lane & 15)) * 32 + krow * 8);

  for (int p = 0; p < NTAP; ++p) {
    if (p) __syncthreads();
    {
      int ky = (NTAP == 9) ? p / 3 : 1, kx = (NTAP == 9) ? p % 3 : 1;
      int y = h + ky - 1;
      bool oky = ((unsigned)y < 64u);
      #pragma unroll
      for (int j = 0; j < 4; ++j) {
        int px = j * 16 + pr;
        int sx = px + kx - 1;
        bool ok = oky && ((unsigned)sx < 64u);
        uint4 v = {0u, 0u, 0u, 0u};
        if (ok) v = *(const uint4*)(an + (((b * 64 + y) * 64 + sx) * 256) + chunk * 8);
        *(uint4*)&sA[px * 256 + ((chunk ^ (px & 7)) * 8)] = v;
      }
    }
    __syncthreads();
    #pragma unroll
    for (int cic = 0; cic < 8; ++cic) {
      const int s = p * 8 + cic;
      if (s < NTAP * 8 - 1) {
        #pragma unroll
        for (int n = 0; n < 2; ++n)
          bu[(cic + 1) & 1][n].u =
              *(const uint4*)(wB + ((s + 1) * 256 + cow + n * 16 + (lane & 15)) * 32 + krow * 8);
      }
      frag_u au[4];
      #pragma unroll
      for (int m = 0; m < 4; ++m)
        au[m].u = *(const uint4*)&sA[(m * 16 + (lane & 15)) * 256 + (((cic * 4 + krow) ^ (lane & 7)) * 8)];
      #pragma unroll
      for (int m = 0; m < 4; ++m)
        #pragma unroll
        for (int n = 0; n < 2; ++n)
          acc[m][n] = __builtin_amdgcn_mfma_f32_16x16x32_f16(au[m].v, bu[cic & 1][n].v, acc[m][n], 0, 0, 0);
    }
  }
  // ---- BN partials from fp32 acc
  const int blk = b * 64 + h;
  #pragma unroll
  for (int n = 0; n < 2; ++n) {
    float s1 = 0.f, s2 = 0.f;
    #pragma unroll
    for (int m = 0; m < 4; ++m)
      #pragma unroll
      for (int r = 0; r < 4; ++r) { float v = acc[m][n][r]; s1 += v; s2 += v * v; }
    s1 += __shfl_xor(s1, 16); s1 += __shfl_xor(s1, 32);
    s2 += __shfl_xor(s2, 16); s2 += __shfl_xor(s2, 32);
    if (lane < 16) {
      int co = cow + n * 16 + lane;
      part[co * 512 + blk] = s1;
      part[131072 + co * 512 + blk] = s2;
    }
  }
  // ---- coalesced fp16 store via LDS transpose
  __syncthreads();
  #pragma unroll
  for (int m = 0; m < 4; ++m) {
    int pxo = m * 16 + (lane >> 4) * 4;
    #pragma unroll
    for (int n = 0; n < 2; ++n) {
      int co = cow + n * 16 + (lane & 15);
      #pragma unroll
      for (int r = 0; r < 4; ++r)
        sA[(pxo + r) * 256 + co] = f2h(acc[m][n][r]);
    }
  }
  __syncthreads();
  const size_t row0 = (size_t)(b * 64 + h) * 64;
  #pragma unroll
  for (int j = 0; j < 4; ++j) {
    int px = j * 16 + pr;
    *(uint4*)&ob[(row0 + px) * 256 + chunk * 8] = *(const uint4*)&sA[px * 256 + chunk * 8];
  }
}

// ---------------- offset/mask conv: grid (8,128) = (b, h*2+half), global-B frags ----------------
__global__ __launch_bounds__(256, 4) void k_convom(const ushort* __restrict__ an,
                                                   const ushort* __restrict__ wB,
                                                   const float* __restrict__ boff,
                                                   const float* __restrict__ bmod,
                                                   float* __restrict__ om) {
  __shared__ __align__(16) ushort sA[32 * 256];
  const int b = blockIdx.x, h = blockIdx.y >> 1, ph = (blockIdx.y & 1) * 32, t = threadIdx.x;
  const int lane = t & 63, wv = t >> 6;
  const int mloc = wv & 1, nt = wv >> 1;
  const int krow = lane >> 4;
  f32x4 acc = (f32x4){0.f, 0.f, 0.f, 0.f};
  const int chunk = t & 31, pr = t >> 5;
  for (int p = 0; p < 9; ++p) {
    if (p) __syncthreads();
    {
      int ky = p / 3, kx = p % 3;
      int y = h + ky - 1;
      bool oky = ((unsigned)y < 64u);
      #pragma unroll
      for (int j = 0; j < 4; ++j) {
        int lpx = j * 8 + pr;
        int sx = ph + lpx + kx - 1;
        bool ok = oky && ((unsigned)sx < 64u);
        uint4 v = {0u, 0u, 0u, 0u};
        if (ok) v = *(const uint4*)(an + (((b * 64 + y) * 64 + sx) * 256) + chunk * 8);
        *(uint4*)&sA[lpx * 256 + ((chunk ^ (lpx & 7)) * 8)] = v;
      }
    }
    __syncthreads();
    #pragma unroll
    for (int cic = 0; cic < 8; ++cic) {
      const int s = p * 8 + cic;
      frag_u bu, au;
      bu.u = *(const uint4*)(wB + ((s * 32 + nt * 16 + (lane & 15)) * 32) + krow * 8);
      int lpx = mloc * 16 + (lane & 15);
      au.u = *(const uint4*)&sA[lpx * 256 + (((cic * 4 + krow) ^ (lpx & 7)) * 8)];
      acc = __builtin_amdgcn_mfma_f32_16x16x32_f16(au.v, bu.v, acc, 0, 0, 0);
    }
  }
  int co = nt * 16 + (lane & 15);
  #pragma unroll
  for (int r = 0; r < 4; ++r) {
    int px = ph + mloc * 16 + (lane >> 4) * 4 + r;
    int row = (b * 64 + h) * 64 + px;
    float v = acc[r];
    float o;
    if (co < 18) o = v + boff[co];
    else if (co < 27) { float mm = v + bmod[co - 18]; o = 2.f / (1.f + __expf(-mm)); }
    else o = 0.f;
    om[row * 32 + co] = o;
  }
}

// ---------------- deformable conv: 512 thr, pk_fma gather, B reg-pipelined ----------------
// grid (8,64) = (b,h) -> XCD = b.
__global__ __launch_bounds__(512, 4) void k_deform(const ushort* __restrict__ an,
                                                   const float* __restrict__ om,
                                                   const ushort* __restrict__ wB,
                                                   ushort* __restrict__ ob,
                                                   float* __restrict__ part) {
  __shared__ __align__(16) ushort sA[64 * 256];
  const int b = blockIdx.x, h = blockIdx.y, t = threadIdx.x;
  const int lane = t & 63, wv = t >> 6;
  const int cow = wv * 32;
  const int krow = lane >> 4;
  const int spx = t & 63, seg = t >> 6;  // seg: 8 segments of 32 channels
  f32x4 acc[4][2];
  #pragma unroll
  for (int m = 0; m < 4; ++m)
    #pragma unroll
    for (int n = 0; n < 2; ++n) acc[m][n] = (f32x4){0.f, 0.f, 0.f, 0.f};

  const ushort* base = an + (size_t)b * PLANE * 256;
  const int row = (b * 64 + h) * 64 + spx;

  // 2-deep B ping-pong, hoisted across taps
  frag_u bu[2][2];
  #pragma unroll
  for (int n = 0; n < 2; ++n)
    bu[0][n].u = *(const uint4*)(wB + (cow + n * 16 + (lane & 15)) * 32 + krow * 8);

  for (int p = 0; p < 9; ++p) {
    if (p) __syncthreads();
    {
      float dy = om[row * 32 + 2 * p];
      float dx = om[row * 32 + 2 * p + 1];
      float mk = om[row * 32 + 18 + p];
      float py = (float)(h + p / 3 - 1) + dy;
      float pxx = (float)(spx + p % 3 - 1) + dx;
      float fy = floorf(py), fx = floorf(pxx);
      float ly = py - fy, lx = pxx - fx;
      int y0 = (int)fy, x0 = (int)fx;
      bool vy0 = ((unsigned)y0 < 64u), vy1 = ((unsigned)(y0 + 1) < 64u);
      bool vx0 = ((unsigned)x0 < 64u), vx1 = ((unsigned)(x0 + 1) < 64u);
      float w00 = (1.f - ly) * (1.f - lx) * mk * ((vy0 && vx0) ? 1.f : 0.f);
      float w01 = (1.f - ly) * lx * mk * ((vy0 && vx1) ? 1.f : 0.f);
      float w10 = ly * (1.f - lx) * mk * ((vy1 && vx0) ? 1.f : 0.f);
      float w11 = ly * lx * mk * ((vy1 && vx1) ? 1.f : 0.f);
      __half2 w00h = __float2half2_rn(w00), w01h = __float2half2_rn(w01);
      __half2 w10h = __float2half2_rn(w10), w11h = __float2half2_rn(w11);
      int y0c = min(max(y0, 0), 63), y1c = min(max(y0 + 1, 0), 63);
      int x0c = min(max(x0, 0), 63), x1c = min(max(x0 + 1, 0), 63);
      const ushort* r00 = base + (y0c * 64 + x0c) * 256 + seg * 32;
      const ushort* r01 = base + (y0c * 64 + x1c) * 256 + seg * 32;
      const ushort* r10 = base + (y1c * 64 + x0c) * 256 + seg * 32;
      const ushort* r11 = base + (y1c * 64 + x1c) * 256 + seg * 32;
      #pragma unroll
      for (int j = 0; j < 4; ++j) {
        uint4 c00 = *(const uint4*)(r00 + j * 8);
        uint4 c01 = *(const uint4*)(r01 + j * 8);
        uint4 c10 = *(const uint4*)(r10 + j * 8);
        uint4 c11 = *(const uint4*)(r11 + j * 8);
        uint ou[4];
        #pragma unroll
        for (int q = 0; q < 4; ++q) {
          __half2 r2 = __hmul2(u2h2(((const uint*)&c00)[q]), w00h);
          r2 = __hfma2(u2h2(((const uint*)&c01)[q]), w01h, r2);
          r2 = __hfma2(u2h2(((const uint*)&c10)[q]), w10h, r2);
          r2 = __hfma2(u2h2(((const uint*)&c11)[q]), w11h, r2);
          ou[q] = h22u(r2);
        }
        *(uint4*)&sA[spx * 256 + (((seg * 4 + j) ^ (spx & 7)) * 8)] = *(uint4*)ou;
      }
    }
    __syncthreads();
    #pragma unroll
    for (int cic = 0; cic < 8; ++cic) {
      const int s = p * 8 + cic;
      if (s < 71) {
        #pragma unroll
        for (int n = 0; n < 2; ++n)
          bu[(cic + 1) & 1][n].u =
              *(const uint4*)(wB + ((s + 1) * 256 + cow + n * 16 + (lane & 15)) * 32 + krow * 8);
      }
      frag_u au[4];
      #pragma unroll
      for (int m = 0; m < 4; ++m)
        au[m].u = *(const uint4*)&sA[(m * 16 + (lane & 15)) * 256 + (((cic * 4 + krow) ^ (lane & 7)) * 8)];
      #pragma unroll
      for (int m = 0; m < 4; ++m)
        #pragma unroll
        for (int n = 0; n < 2; ++n)
          acc[m][n] = __builtin_amdgcn_mfma_f32_16x16x32_f16(au[m].v, bu[cic & 1][n].v, acc[m][n], 0, 0, 0);
    }
  }
  const int blk = b * 64 + h;
  #pragma unroll
  for (int n = 0; n < 2; ++n) {
    float s1 = 0.f, s2 = 0.f;
    #pragma unroll
    for (int m = 0; m < 4; ++m)
      #pragma unroll
      for (int r = 0; r < 4; ++r) { float v = acc[m][n][r]; s1 += v; s2 += v * v; }
    s1 += __shfl_xor(s1, 16); s1 += __shfl_xor(s1, 32);
    s2 += __shfl_xor(s2, 16); s2 += __shfl_xor(s2, 32);
    if (lane < 16) {
      int co = cow + n * 16 + lane;
      part[co * 512 + blk] = s1;
      part[131072 + co * 512 + blk] = s2;
    }
  }
  __syncthreads();
  #pragma unroll
  for (int m = 0; m < 4; ++m) {
    int pxo = m * 16 + (lane >> 4) * 4;
    #pragma unroll
    for (int n = 0; n < 2; ++n) {
      int co = cow + n * 16 + (lane & 15);
      #pragma unroll
      for (int r = 0; r < 4; ++r)
        sA[(pxo + r) * 256 + co] = f2h(acc[m][n][r]);
    }
  }
  __syncthreads();
  const size_t row0 = (size_t)(b * 64 + h) * 64;
  const int chunk = t & 31, pr = t >> 5;
  #pragma unroll
  for (int j = 0; j < 4; ++j) {
    int px = j * 16 + pr;
    *(uint4*)&ob[(row0 + px) * 256 + chunk * 8] = *(const uint4*)&sA[px * 256 + chunk * 8];
  }
}

// ---------------- BN stats final reduce (part transposed: [2][256][512]) ----------------
__global__ void k_statB(const float* __restrict__ part, const float* __restrict__ g,
                        const float* __restrict__ bt, float* __restrict__ scale,
                        float* __restrict__ shift) {
  __shared__ float s2buf[256];
  const int tid = threadIdx.x;
  const int c = tid & 255, which = tid >> 8;
  const float4* p4 = (const float4*)(part + which * 131072 + c * 512);
  float s = 0.f;
  for (int r = 0; r < 128; ++r) { float4 v = p4[r]; s += v.x + v.y + v.z + v.w; }
  if (which) s2buf[c] = s;
  __syncthreads();
  if (!which) {
    const float inv = 1.f / 32768.f;
    float m = s * inv;
    float var = s2buf[c] * inv - m * m;
    float a = g[c] * rsqrtf(var + 1e-5f);
    scale[c] = a;
    shift[c] = bt[c] - m * a;
  }
}

// ---------------- BN+ReLU: t1 fp16 NHWC -> out1 fp16 NHWC ----------------
__global__ void k_bnrelu(const ushort* __restrict__ t, const float* __restrict__ scale,
                         const float* __restrict__ shift, ushort* __restrict__ o) {
  int stride = gridDim.x * blockDim.x;
  for (int i = blockIdx.x * blockDim.x + threadIdx.x; i < 8388608 / 8; i += stride) {
    uint4 v = ((const uint4*)t)[i];
    int c0 = (i & 31) * 8;
    uint ou[4];
    #pragma unroll
    for (int q = 0; q < 4; ++q) {
      float2 f = __half22float2(u2h2(((const uint*)&v)[q]));
      float sa = scale[c0 + 2 * q], sb = scale[c0 + 2 * q + 1];
      float ha = shift[c0 + 2 * q], hb = shift[c0 + 2 * q + 1];
      float qa = fmaxf(f.x * sa + ha, 0.f);
      float qb = fmaxf(f.y * sb + hb, 0.f);
      ou[q] = (uint)f2h(qa) | ((uint)f2h(qb) << 16);
    }
    ((uint4*)o)[i] = *(uint4*)ou;
  }
}

// ---------------- final: relu(bn2(t2)+bn3(res)), fp16 NHWC -> fp32 NCHW ----------------
__global__ __launch_bounds__(256) void k_final(const ushort* __restrict__ t2, const ushort* __restrict__ res,
                                               const float* __restrict__ s2p, const float* __restrict__ sh2p,
                                               const float* __restrict__ s3p, const float* __restrict__ sh3p,
                                               float* __restrict__ o) {
  __shared__ __align__(16) float sT[64 * 68];
  const int b = blockIdx.x, h = blockIdx.y, t = threadIdx.x;
  const int row0 = (b * 64 + h) * 64;
  for (int chunk = 0; chunk < 4; ++chunk) {
    const int c0 = chunk * 64;
    {
      int px = t >> 2, s4 = t & 3;
      int cl = s4 * 16;
      int rbase = (row0 + px) * 256 + c0 + cl;
      uint4 a0 = *(const uint4*)&t2[rbase];
      uint4 a1 = *(const uint4*)&t2[rbase + 8];
      uint4 r0 = *(const uint4*)&res[rbase];
      uint4 r1 = *(const uint4*)&res[rbase + 8];
      #pragma unroll
      for (int q = 0; q < 8; ++q) {
        uint ua = (q < 4) ? ((const uint*)&a0)[q] : ((const uint*)&a1)[q - 4];
        uint ur = (q < 4) ? ((const uint*)&r0)[q] : ((const uint*)&r1)[q - 4];
        float2 fa = __half22float2(u2h2(ua));
        float2 fr = __half22float2(u2h2(ur));
        int ce = cl + 2 * q, codd = ce + 1;
        sT[ce * 68 + px] = fmaxf(fa.x * s2p[c0 + ce] + sh2p[c0 + ce] + fr.x * s3p[c0 + ce] + sh3p[c0 + ce], 0.f);
        sT[codd * 68 + px] = fmaxf(fa.y * s2p[c0 + codd] + sh2p[c0 + codd] + fr.y * s3p[c0 + codd] + sh3p[c0 + codd], 0.f);
      }
    }
    __syncthreads();
    {
      int cl = t & 63, wseg = t >> 6;
      int obase = ((b * 256 + c0 + cl) * 64 + h) * 64 + wseg * 16;
      #pragma unroll
      for (int j = 0; j < 4; ++j) {
        float4 q;
        q.x = sT[cl * 68 + wseg * 16 + j * 4 + 0];
        q.y = sT[cl * 68 + wseg * 16 + j * 4 + 1];
        q.z = sT[cl * 68 + wseg * 16 + j * 4 + 2];
        q.w = sT[cl * 68 + wseg * 16 + j * 4 + 3];
        *(float4*)&o[obase + j * 4] = q;
      }
    }
    __syncthreads();
  }
}

extern "C" void kernel_launch(void* const* d_in, const int* in_sizes, int n_in,
                              void* d_out, int out_size, void* d_ws, size_t ws_size,
                              hipStream_t stream) {
  const float* x    = (const float*)d_in[0];
  const float* w1   = (const float*)d_in[2];
  const float* g1   = (const float*)d_in[4];
  const float* bt1  = (const float*)d_in[5];
  const float* woff = (const float*)d_in[6];
  const float* boff = (const float*)d_in[7];
  const float* wmod = (const float*)d_in[8];
  const float* bmod = (const float*)d_in[9];
  const float* wd   = (const float*)d_in[10];
  const float* g2   = (const float*)d_in[12];
  const float* bt2  = (const float*)d_in[13];
  const float* wds  = (const float*)d_in[14];
  const float* g3   = (const float*)d_in[16];
  const float* bt3  = (const float*)d_in[17];

  float* ws = (float*)d_ws;
  ushort* wb1   = (ushort*)ws;                   // 294912 f32
  ushort* wbd   = (ushort*)(ws + 294912);        // 294912
  ushort* wbom  = (ushort*)(ws + 589824);        // 36864
  ushort* wbds  = (ushort*)(ws + 626688);        // 32768
  float*  SC    = ws + 659456;                   // 2048
  float*  part1 = ws + 661504;                   // 262144
  float*  part2 = ws + 923648;                   // 262144
  float*  part3 = ws + 1185792;                  // 262144
  ushort* xn    = (ushort*)(ws + 1447936);       // 4194304
  ushort* out1  = (ushort*)(ws + 5642240);       // 4194304
  ushort* t1b   = (ushort*)(ws + 9836544);       // 4194304
  ushort* t2b   = (ushort*)(ws + 14030848);      // 4194304
  ushort* resb  = (ushort*)(ws + 18225152);      // 4194304
  float*  om    = ws + 22419456;                 // 1048576

  dim3 gbh(8, 64);
  k_prep<<<512, 256, 0, stream>>>(w1, wd, woff, wmod, wds, wb1, wbd, wbom, wbds);
  k_x2nhwc<<<gbh, 256, 0, stream>>>(x, xn);
  k_convbig<9><<<gbh, 512, 0, stream>>>(xn, wb1, t1b, part1);
  k_statB<<<1, 512, 0, stream>>>(part1, g1, bt1, SC, SC + 256);
  k_bnrelu<<<2048, 256, 0, stream>>>(t1b, SC, SC + 256, out1);
  k_convom<<<dim3(8, 128), 256, 0, stream>>>(out1, wbom, boff, bmod, om);
  k_deform<<<gbh, 512, 0, stream>>>(out1, om, wbd, t2b, part2);
  k_statB<<<1, 512, 0, stream>>>(part2, g2, bt2, SC + 512, SC + 768);
  k_convbig<1><<<gbh, 512, 0, stream>>>(xn, wbds, resb, part3);
  k_statB<<<1, 512, 0, stream>>>(part3, g3, bt3, SC + 1024, SC + 1280);
  k_final<<<gbh, 256, 0, stream>>>(t2b, resb, SC + 512, SC + 768, SC + 1024, SC + 1280, (float*)d_out);
}